// Round 10
// baseline (444.064 us; speedup 1.0000x reference)
//
#include <hip/hip_runtime.h>
#include <hip/hip_bf16.h>
#include <stdint.h>

#define BATCH 128
#define SEQ   512
#define NW    6
#define DIM   64
#define NELEM (BATCH * SEQ * NW)   // 393216
#define PI_F  3.14159265358979323846f
#define MSTRIDE 100                // LDS row stride (words) for 48 staged cols

typedef float v2f __attribute__((ext_vector_type(2)));

__device__ __forceinline__ v2f pkfma(float s, v2f m, v2f a) {
    return __builtin_elementwise_fma((v2f){s, s}, m, a);
}

// ---------------------------------------------------------------------------
// Interleaved 6-way DPP wave-64 reduction (VALU pipe). Totals land in lane 63.
// ---------------------------------------------------------------------------
template <int CTRL>
__device__ __forceinline__ void red_stage6(float v[6]) {
#pragma unroll
    for (int w = 0; w < 6; ++w)
        v[w] += __int_as_float(__builtin_amdgcn_update_dpp(
            0, __float_as_int(v[w]), CTRL, 0xF, 0xF, false));
}

// Branch-free sincos(h/2) for |h| <= 1 (h is a bounded expectation value).
__device__ __forceinline__ void sincos_half(float h, float& s, float& c) {
    const float u = h * h;
    c = fmaf(u, fmaf(u, fmaf(u, -2.1701389e-5f, 2.6041667e-3f), -0.125f), 1.0f);
    s = h * fmaf(u, fmaf(u, fmaf(u, -1.5501e-6f, 2.6041667e-4f), -2.0833333e-2f), 0.5f);
}

// ---------------------------------------------------------------------------
// Kernel 1: bf16-vs-f32 detection on `angles` (U(0,pi) data).
// ---------------------------------------------------------------------------
__global__ void k_detect(const uint32_t* __restrict__ a, int* __restrict__ flag) {
    __shared__ int cnt;
    if (threadIdx.x == 0) cnt = 0;
    __syncthreads();
    uint32_t w = a[threadIdx.x];
    uint32_t e = (w >> 8) & 0xFFu;
    if (e >= 0x3Au && e <= 0x41u) atomicAdd(&cnt, 1);
    __syncthreads();
    if (threadIdx.x == 0) *flag = (cnt >= 128) ? 1 : 0;   // 1 = bf16
}

__device__ __forceinline__ float ldf(const void* p, int i, bool bf) {
    if (bf) {
        uint32_t u = (uint32_t)((const uint16_t*)p)[i];
        return __uint_as_float(u << 16);
    }
    return ((const float*)p)[i];
}

// ---------------------------------------------------------------------------
// Kernel 2: inputs -> f32 ws; precompute cos(x), sin(x) (full angle).
// ---------------------------------------------------------------------------
__global__ void k_convert(const void* ang, const void* poly, const void* fp,
                          const void* bp, const void* fc, const void* bc,
                          float* __restrict__ cs, float* __restrict__ misc,
                          const int* __restrict__ flag) {
    const bool bf = (*flag != 0);
    const int i = blockIdx.x * blockDim.x + threadIdx.x;
    if (i < NELEM) {
        float x = ldf(ang, i, bf);
        float s, c;
        __sincosf(x, &s, &c);
        cs[2 * i]     = c;
        cs[2 * i + 1] = s;
    }
    if (i < 4)                    misc[i]            = ldf(poly, i, bf);
    else if (i >= 64 && i < 100)  misc[4 + (i - 64)] = ldf(fp, i - 64, bf);
    else if (i >= 128 && i < 164) misc[40 + (i - 128)] = ldf(bp, i - 128, bf);
    else if (i == 200)            misc[76] = ldf(fc, 0, bf);
    else if (i == 201)            misc[77] = ldf(bc, 0, bf);
}

// ---------------------------------------------------------------------------
// Kernel 3: precompute M[dir] as an explicit 64x64 complex matrix.
// Mg layout: [dir][row][col][2] floats. Runs once; perf-irrelevant.
// ---------------------------------------------------------------------------
__global__ void __launch_bounds__(64) k_msetup(const float* __restrict__ misc,
                                               float* __restrict__ Mg) {
    const int p   = threadIdx.x;
    const int col = blockIdx.x & 63;
    const int dir = blockIdx.x >> 6;
    const float* poly = misc;
    const float* prm  = misc + (dir ? 40 : 4);

    float yr = (p == col) ? 1.f : 0.f;
    float yi = 0.f;

#pragma unroll
    for (int d = 0; d < 4; ++d) {
        const float th = 0.5f * PI_F * poly[d] *
                         (float)(6 - 2 * (int)__popc((unsigned)p));
        float s, c;
        __sincosf(th, &s, &c);
        const float nr = yr * c + yi * s;
        const float ni = yi * c - yr * s;
        yr = nr; yi = ni;
#pragma unroll
        for (int k = 0; k < 6; ++k) {
            const int cw = k, tw = (k + 1) % 6;
            const int src = p ^ (((p >> (5 - cw)) & 1) << (5 - tw));
            yr = __shfl(yr, src, 64);
            yi = __shfl(yi, src, 64);
        }
    }

    int idx = 0;
#pragma unroll
    for (int l = 0; l < 2; ++l) {
#pragma unroll
        for (int w = 0; w < 6; ++w) {
            float cx, sx, cy, sy, cz, sz;
            __sincosf(0.5f * prm[idx + 0], &sx, &cx);
            __sincosf(0.5f * prm[idx + 1], &sy, &cy);
            __sincosf(0.5f * prm[idx + 2], &sz, &cz);
            idx += 3;
            const float A = cy * cx, B = sy * sx, C = sy * cx, D = cy * sx;
            const float U00r = cz * A + sz * B, U00i = cz * B - sz * A;
            const float U11r = U00r,            U11i = sz * A - cz * B;
            const float Xr   = cz * C + sz * D, Xi   = sz * C - cz * D;
            const int m  = 1 << (5 - w);
            const int bb = (p >> (5 - w)) & 1;
            const float C1r = bb ? U11r : U00r;
            const float C1i = bb ? U11i : U00i;
            const float C2r = bb ? Xr : -Xr;
            const float C2i = Xi;
            const float pr = __shfl_xor(yr, m, 64);
            const float pi = __shfl_xor(yi, m, 64);
            const float nr = C1r * yr - C1i * yi + C2r * pr - C2i * pi;
            const float ni = C1r * yi + C1i * yr + C2r * pi + C2i * pr;
            yr = nr; yi = ni;
        }
#pragma unroll
        for (int k = 0; k < 5; ++k) {
            const int src = p ^ (((p >> (5 - k)) & 1) << (5 - (k + 1)));
            yr = __shfl(yr, src, 64);
            yi = __shfl(yi, src, 64);
        }
    }

    float* out = Mg + ((size_t)(dir * 64 + p) * 64 + (size_t)col) * 2;
    out[0] = yr;
    out[1] = yi;
}

// ---------------------------------------------------------------------------
// Kernel 4: recurrent sim. ONE WAVE per chain, no barriers in the loop.
// vs r9 (instruction-stream diet):
//  - packed v_pk_fma_f32 matvec (v2f + __builtin_elementwise_fma)
//  - 16 M-columns register-resident (32 VGPRs, proven safe r6-r8); 48 via
//    24 ds_read_b128 issued at body top (encode hides their latency)
//  - pointer-walked cs/zb (no per-step dir selects), 2x unrolled loop with
//    alternating xq register sets (no copy chain), hoisted bpermute addrs
// ---------------------------------------------------------------------------
__global__ void __launch_bounds__(64, 1) k_sim(const float* __restrict__ cs,
                                               const float* __restrict__ Mg,
                                               float* __restrict__ hbuf) {
    const int lane  = threadIdx.x;
    const int chain = blockIdx.x;            // 0..255
    const int dir   = chain >> 7;
    const int b     = chain & 127;
    float* orow = hbuf + (size_t)dir * NELEM + (size_t)b * (SEQ * NW);
    const float* csrow = cs + (size_t)b * (SEQ * NW * 2);

    __shared__ float Ml[DIM * MSTRIDE];      // 25.6 KB staged M cols 16..63
    __shared__ float zb[SEQ * NW];           // 12 KB output buffer

    // ---- stage cols 16..63 of my row into LDS; cols 0..15 into VGPRs ----
    {
        const float4* mrow =
            (const float4*)(Mg + (size_t)(dir * 64 + lane) * 128 + 32);
        float4* dst = (float4*)(Ml + lane * MSTRIDE);
#pragma unroll
        for (int k = 0; k < 24; ++k) dst[k] = mrow[k];
    }
    v2f Mres[16];
    {
        const float2* mr2 = (const float2*)(Mg + (size_t)(dir * 64 + lane) * 128);
#pragma unroll
        for (int k = 0; k < 16; ++k) Mres[k] = (v2f){mr2[k].x, mr2[k].y};
    }
    __syncthreads();                         // once; orders staging vs reads

    int zmask[6], bpa[6];
#pragma unroll
    for (int w = 0; w < 6; ++w) {
        zmask[w] = ((lane >> (5 - w)) & 1) << 31;
        bpa[w]   = (lane ^ (1 << (5 - w))) << 2;   // hoisted bpermute addr
    }

    float h[6] = {0.f, 0.f, 0.f, 0.f, 0.f, 0.f};

    const float4* Mrow4 = (const float4*)(Ml + lane * MSTRIDE);

    // walking pointers (no per-step index math)
    const float* cp = csrow + (dir ? (SEQ - 1) * 12 : 0);
    const int   cstep = dir ? -12 : 12;
    float*       zp = zb + (dir ? (SEQ - 1) * NW : 0);
    const int   zstep = dir ? -NW : NW;

    // ---- one simulation step (xq in registers; writes zp; updates h) ----
    auto step = [&](const float4 xq0, const float4 xq1, const float4 xq2,
                    float* zout) {
        // issue LDS reads for M cols 16..63 first (latency hidden by encode)
        float4 mb[24];
#pragma unroll
        for (int k = 0; k < 24; ++k) mb[k] = Mrow4[k];

        // encode: tensor factors
        float cw6[6], sw6[6];
#pragma unroll
        for (int w = 0; w < 6; ++w) sincos_half(h[w], sw6[w], cw6[w]);
        float G[8], L[8];
        {
            const float g00 = cw6[0] * cw6[1], g01 = cw6[0] * sw6[1];
            const float g10 = sw6[0] * cw6[1], g11 = sw6[0] * sw6[1];
            G[0] = g00 * cw6[2]; G[1] = g00 * sw6[2];
            G[2] = g01 * cw6[2]; G[3] = g01 * sw6[2];
            G[4] = g10 * cw6[2]; G[5] = g10 * sw6[2];
            G[6] = g11 * cw6[2]; G[7] = g11 * sw6[2];
            const float l00 = cw6[3] * cw6[4], l01 = cw6[3] * sw6[4];
            const float l10 = sw6[3] * cw6[4], l11 = sw6[3] * sw6[4];
            L[0] = l00 * cw6[5]; L[1] = l00 * sw6[5];
            L[2] = l01 * cw6[5]; L[3] = l01 * sw6[5];
            L[4] = l10 * cw6[5]; L[5] = l10 * sw6[5];
            L[6] = l11 * cw6[5]; L[7] = l11 * sw6[5];
        }

        // matvec: resident half (a=0,1), then LDS half (a=2..7)
        v2f y = {0.f, 0.f};
#pragma unroll
        for (int a = 0; a < 2; ++a) {
            v2f T = {0.f, 0.f};
#pragma unroll
            for (int bb2 = 0; bb2 < 8; ++bb2)
                T = pkfma(L[bb2], Mres[8 * a + bb2], T);
            y = pkfma(G[a], T, y);
        }
#pragma unroll
        for (int a = 2; a < 8; ++a) {
            const int o = 4 * a - 8;
            v2f T = {0.f, 0.f};
            T = pkfma(L[0], (v2f){mb[o + 0].x, mb[o + 0].y}, T);
            T = pkfma(L[1], (v2f){mb[o + 0].z, mb[o + 0].w}, T);
            T = pkfma(L[2], (v2f){mb[o + 1].x, mb[o + 1].y}, T);
            T = pkfma(L[3], (v2f){mb[o + 1].z, mb[o + 1].w}, T);
            T = pkfma(L[4], (v2f){mb[o + 2].x, mb[o + 2].y}, T);
            T = pkfma(L[5], (v2f){mb[o + 2].z, mb[o + 2].w}, T);
            T = pkfma(L[6], (v2f){mb[o + 3].x, mb[o + 3].y}, T);
            T = pkfma(L[7], (v2f){mb[o + 3].z, mb[o + 3].w}, T);
            y = pkfma(G[a], T, y);
        }
        const float yr = y.x, yi = y.y;

        // measurement: batched partner shuffles (hoisted addresses)
        float pr[6], pi[6];
#pragma unroll
        for (int w = 0; w < 6; ++w)
            pr[w] = __int_as_float(
                __builtin_amdgcn_ds_bpermute(bpa[w], __float_as_int(yr)));
#pragma unroll
        for (int w = 0; w < 6; ++w)
            pi[w] = __int_as_float(
                __builtin_amdgcn_ds_bpermute(bpa[w], __float_as_int(yi)));

        const float q = yr * yr + yi * yi;
        float cxw[6], sxw[6];
        cxw[0] = xq0.x; sxw[0] = xq0.y; cxw[1] = xq0.z; sxw[1] = xq0.w;
        cxw[2] = xq1.x; sxw[2] = xq1.y; cxw[3] = xq1.z; sxw[3] = xq1.w;
        cxw[4] = xq2.x; sxw[4] = xq2.y; cxw[5] = xq2.z; sxw[5] = xq2.w;

        float v[6];
#pragma unroll
        for (int w = 0; w < 6; ++w) {
            const float ac = yr * pr[w] + yi * pi[w];
            const float sq = __int_as_float(__float_as_int(q) ^ zmask[w]);
            v[w] = cxw[w] * sq - sxw[w] * ac;
        }

        red_stage6<0x111>(v);   // row_shr:1
        red_stage6<0x112>(v);   // row_shr:2
        red_stage6<0x114>(v);   // row_shr:4
        red_stage6<0x118>(v);   // row_shr:8
        red_stage6<0x142>(v);   // row_bcast:15
        red_stage6<0x143>(v);   // row_bcast:31

        if (lane == 63) {
#pragma unroll
            for (int w = 0; w < 6; ++w) zout[w] = v[w];
        }
#pragma unroll
        for (int w = 0; w < 6; ++w)
            h[w] = __int_as_float(
                __builtin_amdgcn_readlane(__float_as_int(v[w]), 63));
    };

    // ---- 2x-unrolled recurrent loop (alternating xq register sets) ----
    float4 xa0 = ((const float4*)cp)[0];
    float4 xa1 = ((const float4*)cp)[1];
    float4 xa2 = ((const float4*)cp)[2];

    for (int t = 0; t < SEQ; t += 2) {
        const float* cp1 = cp + cstep;
        const float4 xb0 = ((const float4*)cp1)[0];
        const float4 xb1 = ((const float4*)cp1)[1];
        const float4 xb2 = ((const float4*)cp1)[2];

        step(xa0, xa1, xa2, zp);
        zp += zstep;

        const float* cp2 = cp + 2 * cstep;     // last iter reads the ws pad
        xa0 = ((const float4*)cp2)[0];
        xa1 = ((const float4*)cp2)[1];
        xa2 = ((const float4*)cp2)[2];

        step(xb0, xb1, xb2, zp);
        zp += zstep;
        cp = cp2;
    }
    __syncthreads();                         // order zb writes vs bulk read

    // ---- bulk store outputs: 3072 floats = 768 float4 over 64 lanes ----
    {
        const float4* zs4 = (const float4*)zb;
        float4* go = (float4*)orow;
#pragma unroll
        for (int k = 0; k < 12; ++k) {
            const int idx = lane + k * 64;
            go[idx] = zs4[idx];
        }
    }
}

// ---------------------------------------------------------------------------
// Kernel 5: out = sigmoid(fc)*h_fwd + sigmoid(bc)*h_bwd, dtype per flag.
// ---------------------------------------------------------------------------
__global__ void k_combine(const float* __restrict__ hbuf,
                          const float* __restrict__ misc,
                          void* __restrict__ out, const int* __restrict__ flag) {
    const int i = blockIdx.x * blockDim.x + threadIdx.x;
    if (i >= NELEM) return;
    const float sf = 1.f / (1.f + __expf(-misc[76]));
    const float sb = 1.f / (1.f + __expf(-misc[77]));
    const float v = sf * hbuf[i] + sb * hbuf[NELEM + i];
    if (*flag) ((__hip_bfloat16*)out)[i] = __float2bfloat16(v);
    else       ((float*)out)[i] = v;
}

// ---------------------------------------------------------------------------
extern "C" void kernel_launch(void* const* d_in, const int* in_sizes, int n_in,
                              void* d_out, int out_size, void* d_ws, size_t ws_size,
                              hipStream_t stream) {
    const void* ang  = d_in[0];
    const void* poly = d_in[1];
    const void* fp   = d_in[2];
    const void* bp   = d_in[3];
    const void* fc   = d_in[4];
    const void* bc   = d_in[5];

    // ws (floats): pad[32] | cs[2*NELEM] | misc[128] | hbuf[2*NELEM] |
    //              M[16384] | flag   (pad absorbs the unrolled prefetch OOB)
    float* cs   = (float*)d_ws + 32;
    float* misc = cs + 2 * NELEM;
    float* hbuf = misc + 128;
    float* Mg   = hbuf + 2 * NELEM;
    int*   flag = (int*)(Mg + 2 * 64 * 64 * 2);

    k_detect<<<1, 256, 0, stream>>>((const uint32_t*)ang, flag);
    k_convert<<<(NELEM + 255) / 256, 256, 0, stream>>>(ang, poly, fp, bp, fc, bc,
                                                       cs, misc, flag);
    k_msetup<<<128, 64, 0, stream>>>(misc, Mg);
    k_sim<<<256, 64, 0, stream>>>(cs, Mg, hbuf);
    k_combine<<<(NELEM + 255) / 256, 256, 0, stream>>>(hbuf, misc, d_out, flag);
}

// Round 11
// 420.399 us; speedup vs baseline: 1.0563x; 1.0563x over previous
//
#include <hip/hip_runtime.h>
#include <hip/hip_bf16.h>
#include <stdint.h>

#define BATCH 128
#define SEQ   512
#define NW    6
#define DIM   64
#define NELEM (BATCH * SEQ * NW)   // 393216
#define PI_F  3.14159265358979323846f

typedef float v2f __attribute__((ext_vector_type(2)));

__device__ __forceinline__ v2f pkfma(float s, v2f m, v2f a) {
    return __builtin_elementwise_fma((v2f){s, s}, m, a);
}

// ---------------------------------------------------------------------------
// Interleaved 6-way DPP wave-64 reduction (VALU pipe). Totals land in lane 63.
// ---------------------------------------------------------------------------
template <int CTRL>
__device__ __forceinline__ void red_stage6(float v[6]) {
#pragma unroll
    for (int w = 0; w < 6; ++w)
        v[w] += __int_as_float(__builtin_amdgcn_update_dpp(
            0, __float_as_int(v[w]), CTRL, 0xF, 0xF, false));
}

// Branch-free sincos(h/2) for |h| <= 1 (h is a bounded expectation value).
__device__ __forceinline__ void sincos_half(float h, float& s, float& c) {
    const float u = h * h;
    c = fmaf(u, fmaf(u, fmaf(u, -2.1701389e-5f, 2.6041667e-3f), -0.125f), 1.0f);
    s = h * fmaf(u, fmaf(u, fmaf(u, -1.5501e-6f, 2.6041667e-4f), -2.0833333e-2f), 0.5f);
}

// ---------------------------------------------------------------------------
// Kernel 1: bf16-vs-f32 detection on `angles` (U(0,pi) data).
// ---------------------------------------------------------------------------
__global__ void k_detect(const uint32_t* __restrict__ a, int* __restrict__ flag) {
    __shared__ int cnt;
    if (threadIdx.x == 0) cnt = 0;
    __syncthreads();
    uint32_t w = a[threadIdx.x];
    uint32_t e = (w >> 8) & 0xFFu;
    if (e >= 0x3Au && e <= 0x41u) atomicAdd(&cnt, 1);
    __syncthreads();
    if (threadIdx.x == 0) *flag = (cnt >= 128) ? 1 : 0;   // 1 = bf16
}

__device__ __forceinline__ float ldf(const void* p, int i, bool bf) {
    if (bf) {
        uint32_t u = (uint32_t)((const uint16_t*)p)[i];
        return __uint_as_float(u << 16);
    }
    return ((const float*)p)[i];
}

// ---------------------------------------------------------------------------
// Kernel 2: inputs -> f32 ws; precompute cos(x), sin(x) (full angle).
// ---------------------------------------------------------------------------
__global__ void k_convert(const void* ang, const void* poly, const void* fp,
                          const void* bp, const void* fc, const void* bc,
                          float* __restrict__ cs, float* __restrict__ misc,
                          const int* __restrict__ flag) {
    const bool bf = (*flag != 0);
    const int i = blockIdx.x * blockDim.x + threadIdx.x;
    if (i < NELEM) {
        float x = ldf(ang, i, bf);
        float s, c;
        __sincosf(x, &s, &c);
        cs[2 * i]     = c;
        cs[2 * i + 1] = s;
    }
    if (i < 4)                    misc[i]            = ldf(poly, i, bf);
    else if (i >= 64 && i < 100)  misc[4 + (i - 64)] = ldf(fp, i - 64, bf);
    else if (i >= 128 && i < 164) misc[40 + (i - 128)] = ldf(bp, i - 128, bf);
    else if (i == 200)            misc[76] = ldf(fc, 0, bf);
    else if (i == 201)            misc[77] = ldf(bc, 0, bf);
}

// ---------------------------------------------------------------------------
// Kernel 3: precompute M[dir] as an explicit 64x64 complex matrix.
// Mg layout: [dir][row][col][2] floats. Runs once; perf-irrelevant.
// ---------------------------------------------------------------------------
__global__ void __launch_bounds__(64) k_msetup(const float* __restrict__ misc,
                                               float* __restrict__ Mg) {
    const int p   = threadIdx.x;
    const int col = blockIdx.x & 63;
    const int dir = blockIdx.x >> 6;
    const float* poly = misc;
    const float* prm  = misc + (dir ? 40 : 4);

    float yr = (p == col) ? 1.f : 0.f;
    float yi = 0.f;

#pragma unroll
    for (int d = 0; d < 4; ++d) {
        const float th = 0.5f * PI_F * poly[d] *
                         (float)(6 - 2 * (int)__popc((unsigned)p));
        float s, c;
        __sincosf(th, &s, &c);
        const float nr = yr * c + yi * s;
        const float ni = yi * c - yr * s;
        yr = nr; yi = ni;
#pragma unroll
        for (int k = 0; k < 6; ++k) {
            const int cw = k, tw = (k + 1) % 6;
            const int src = p ^ (((p >> (5 - cw)) & 1) << (5 - tw));
            yr = __shfl(yr, src, 64);
            yi = __shfl(yi, src, 64);
        }
    }

    int idx = 0;
#pragma unroll
    for (int l = 0; l < 2; ++l) {
#pragma unroll
        for (int w = 0; w < 6; ++w) {
            float cx, sx, cy, sy, cz, sz;
            __sincosf(0.5f * prm[idx + 0], &sx, &cx);
            __sincosf(0.5f * prm[idx + 1], &sy, &cy);
            __sincosf(0.5f * prm[idx + 2], &sz, &cz);
            idx += 3;
            const float A = cy * cx, B = sy * sx, C = sy * cx, D = cy * sx;
            const float U00r = cz * A + sz * B, U00i = cz * B - sz * A;
            const float U11r = U00r,            U11i = sz * A - cz * B;
            const float Xr   = cz * C + sz * D, Xi   = sz * C - cz * D;
            const int m  = 1 << (5 - w);
            const int bb = (p >> (5 - w)) & 1;
            const float C1r = bb ? U11r : U00r;
            const float C1i = bb ? U11i : U00i;
            const float C2r = bb ? Xr : -Xr;
            const float C2i = Xi;
            const float pr = __shfl_xor(yr, m, 64);
            const float pi = __shfl_xor(yi, m, 64);
            const float nr = C1r * yr - C1i * yi + C2r * pr - C2i * pi;
            const float ni = C1r * yi + C1i * yr + C2r * pi + C2i * pr;
            yr = nr; yi = ni;
        }
#pragma unroll
        for (int k = 0; k < 5; ++k) {
            const int src = p ^ (((p >> (5 - k)) & 1) << (5 - (k + 1)));
            yr = __shfl(yr, src, 64);
            yi = __shfl(yi, src, 64);
        }
    }

    float* out = Mg + ((size_t)(dir * 64 + p) * 64 + (size_t)col) * 2;
    out[0] = yr;
    out[1] = yi;
}

// ---------------------------------------------------------------------------
// Kernel 4: recurrent sim. TWO WAVES per chain; wave wv owns M columns
// [32wv, 32wv+32) fully register-resident (64 VGPRs — between proven-32 and
// the r4 spill wall at 128). Zero per-step M LDS traffic (r9/r10's whale).
// Exchange per step: my partial stays in registers; ONE ds_write_b64 + ONE
// ds_read_b64 moves the partner's. One barrier/step (ping-pong pY).
// Measurement (bpermute + DPP + readlane) redundant on both waves — parallel
// issue, no added latency. cs staged in LDS, outputs buffered in LDS.
// ---------------------------------------------------------------------------
__global__ void __launch_bounds__(128, 1) k_sim(const float* __restrict__ cs,
                                                const float* __restrict__ Mg,
                                                float* __restrict__ hbuf) {
    const int tid   = threadIdx.x;
    const int lane  = tid & 63;
    const int wv    = tid >> 6;              // wave 0..1
    const int chain = blockIdx.x;            // 0..255
    const int dir   = chain >> 7;
    const int b     = chain & 127;
    float* orow = hbuf + (size_t)dir * NELEM + (size_t)b * (SEQ * NW);
    const float* csrow = cs + (size_t)b * (SEQ * NW * 2);

    __shared__ float  cl[SEQ * 12];          // 24 KB staged cos/sin(x)
    __shared__ float  zb[SEQ * NW];          // 12 KB output buffer
    __shared__ float2 pY[2][2][DIM];         // [buf][wave][lane] partials 2 KB

    // ---- stage this chain's cos/sin rows into LDS (once) ----
    {
        const float4* src = (const float4*)csrow;   // 1536 float4
        float4* dst = (float4*)cl;
#pragma unroll
        for (int k = 0; k < 12; ++k) {
            const int idx = tid + k * 128;
            dst[idx] = src[idx];
        }
    }

    // ---- my 32 resident M columns: row = lane, cols = 32wv..32wv+31 ----
    v2f Mres[32];
    {
        const float2* mr2 =
            (const float2*)(Mg + (size_t)(dir * 64 + lane) * 128 + 64 * wv);
#pragma unroll
        for (int k = 0; k < 32; ++k) Mres[k] = (v2f){mr2[k].x, mr2[k].y};
    }

    int zmask[6], bpa[6];
#pragma unroll
    for (int w = 0; w < 6; ++w) {
        zmask[w] = ((lane >> (5 - w)) & 1) << 31;
        bpa[w]   = (lane ^ (1 << (5 - w))) << 2;   // hoisted bpermute addr
    }

    float h[6] = {0.f, 0.f, 0.f, 0.f, 0.f, 0.f};

    // encode h -> my half-matvec partial (all in registers; no LDS for x)
    auto encode_matvec = [&](v2f& acc) {
        float cw6[6], sw6[6];
#pragma unroll
        for (int w = 0; w < 6; ++w) sincos_half(h[w], sw6[w], cw6[w]);
        float L[8];
        {
            const float l00 = cw6[3] * cw6[4], l01 = cw6[3] * sw6[4];
            const float l10 = sw6[3] * cw6[4], l11 = sw6[3] * sw6[4];
            L[0] = l00 * cw6[5]; L[1] = l00 * sw6[5];
            L[2] = l01 * cw6[5]; L[3] = l01 * sw6[5];
            L[4] = l10 * cw6[5]; L[5] = l10 * sw6[5];
            L[6] = l11 * cw6[5]; L[7] = l11 * sw6[5];
        }
        const float gw0 = wv ? sw6[0] : cw6[0];        // wire 0 = my half
        const float g0  = gw0 * cw6[1], g1 = gw0 * sw6[1];
        float GH[4];
        GH[0] = g0 * cw6[2]; GH[1] = g0 * sw6[2];
        GH[2] = g1 * cw6[2]; GH[3] = g1 * sw6[2];
        v2f y = {0.f, 0.f};
#pragma unroll
        for (int j = 0; j < 4; ++j) {
            v2f T = {0.f, 0.f};
#pragma unroll
            for (int bb2 = 0; bb2 < 8; ++bb2)
                T = pkfma(L[bb2], Mres[8 * j + bb2], T);
            y = pkfma(GH[j], T, y);
        }
        acc = y;
    };

    // walking pointers (no per-step index math)
    const float* cp = cl + (dir ? (SEQ - 1) * 12 : 0);
    const int   cstep = dir ? -12 : 12;
    float*       zp = zb + (dir ? (SEQ - 1) * NW : 0);
    const int   zstep = dir ? -NW : NW;

    __syncthreads();                         // staging + Mres visible

    // ---- peel: partial for the t=0 state (h = 0) ----
    v2f myacc;
    encode_matvec(myacc);
    pY[0][wv][lane] = (float2){myacc.x, myacc.y};
    __syncthreads();

    for (int t = 0; t < SEQ; ++t) {
        const int buf = t & 1;

        // issue LDS reads early: this step's cos/sin + partner's partial
        const float4 xq0 = ((const float4*)cp)[0];
        const float4 xq1 = ((const float4*)cp)[1];
        const float4 xq2 = ((const float4*)cp)[2];
        cp += cstep;
        const float2 yo = pY[buf][wv ^ 1][lane];

        const float yr = myacc.x + yo.x;
        const float yi = myacc.y + yo.y;

        // measurement: batched partner shuffles (hoisted addresses)
        float pr[6], pi[6];
#pragma unroll
        for (int w = 0; w < 6; ++w)
            pr[w] = __int_as_float(
                __builtin_amdgcn_ds_bpermute(bpa[w], __float_as_int(yr)));
#pragma unroll
        for (int w = 0; w < 6; ++w)
            pi[w] = __int_as_float(
                __builtin_amdgcn_ds_bpermute(bpa[w], __float_as_int(yi)));

        const float q = yr * yr + yi * yi;
        float cxw[6], sxw[6];
        cxw[0] = xq0.x; sxw[0] = xq0.y; cxw[1] = xq0.z; sxw[1] = xq0.w;
        cxw[2] = xq1.x; sxw[2] = xq1.y; cxw[3] = xq1.z; sxw[3] = xq1.w;
        cxw[4] = xq2.x; sxw[4] = xq2.y; cxw[5] = xq2.z; sxw[5] = xq2.w;

        float v[6];
#pragma unroll
        for (int w = 0; w < 6; ++w) {
            const float ac = yr * pr[w] + yi * pi[w];
            const float sq = __int_as_float(__float_as_int(q) ^ zmask[w]);
            v[w] = cxw[w] * sq - sxw[w] * ac;
        }

        red_stage6<0x111>(v);   // row_shr:1
        red_stage6<0x112>(v);   // row_shr:2
        red_stage6<0x114>(v);   // row_shr:4
        red_stage6<0x118>(v);   // row_shr:8
        red_stage6<0x142>(v);   // row_bcast:15
        red_stage6<0x143>(v);   // row_bcast:31

        if (tid == 63) {        // wave0 lane63 buffers outputs
#pragma unroll
            for (int w = 0; w < 6; ++w) zp[w] = v[w];
        }
        zp += zstep;

#pragma unroll
        for (int w = 0; w < 6; ++w)
            h[w] = __int_as_float(
                __builtin_amdgcn_readlane(__float_as_int(v[w]), 63));

        // next state's partial into the other buffer (registers + 1 write)
        encode_matvec(myacc);
        pY[buf ^ 1][wv][lane] = (float2){myacc.x, myacc.y};
        __syncthreads();        // the ONLY barrier per step
    }

    // ---- bulk store outputs: 3072 floats = 768 float4 over 128 threads ----
    {
        const float4* zs4 = (const float4*)zb;
        float4* go = (float4*)orow;
#pragma unroll
        for (int k = 0; k < 6; ++k) {
            const int idx = tid + k * 128;
            go[idx] = zs4[idx];
        }
    }
}

// ---------------------------------------------------------------------------
// Kernel 5: out = sigmoid(fc)*h_fwd + sigmoid(bc)*h_bwd, dtype per flag.
// ---------------------------------------------------------------------------
__global__ void k_combine(const float* __restrict__ hbuf,
                          const float* __restrict__ misc,
                          void* __restrict__ out, const int* __restrict__ flag) {
    const int i = blockIdx.x * blockDim.x + threadIdx.x;
    if (i >= NELEM) return;
    const float sf = 1.f / (1.f + __expf(-misc[76]));
    const float sb = 1.f / (1.f + __expf(-misc[77]));
    const float v = sf * hbuf[i] + sb * hbuf[NELEM + i];
    if (*flag) ((__hip_bfloat16*)out)[i] = __float2bfloat16(v);
    else       ((float*)out)[i] = v;
}

// ---------------------------------------------------------------------------
extern "C" void kernel_launch(void* const* d_in, const int* in_sizes, int n_in,
                              void* d_out, int out_size, void* d_ws, size_t ws_size,
                              hipStream_t stream) {
    const void* ang  = d_in[0];
    const void* poly = d_in[1];
    const void* fp   = d_in[2];
    const void* bp   = d_in[3];
    const void* fc   = d_in[4];
    const void* bc   = d_in[5];

    // ws (floats): pad[32] | cs[2*NELEM] | misc[128] | hbuf[2*NELEM] |
    //              M[16384] | flag
    float* cs   = (float*)d_ws + 32;
    float* misc = cs + 2 * NELEM;
    float* hbuf = misc + 128;
    float* Mg   = hbuf + 2 * NELEM;
    int*   flag = (int*)(Mg + 2 * 64 * 64 * 2);

    k_detect<<<1, 256, 0, stream>>>((const uint32_t*)ang, flag);
    k_convert<<<(NELEM + 255) / 256, 256, 0, stream>>>(ang, poly, fp, bp, fc, bc,
                                                       cs, misc, flag);
    k_msetup<<<128, 64, 0, stream>>>(misc, Mg);
    k_sim<<<256, 128, 0, stream>>>(cs, Mg, hbuf);
    k_combine<<<(NELEM + 255) / 256, 256, 0, stream>>>(hbuf, misc, d_out, flag);
}

// Round 12
// 364.513 us; speedup vs baseline: 1.2182x; 1.1533x over previous
//
#include <hip/hip_runtime.h>
#include <hip/hip_bf16.h>
#include <stdint.h>

#define BATCH 128
#define SEQ   512
#define NW    6
#define DIM   64
#define NELEM (BATCH * SEQ * NW)   // 393216
#define PI_F  3.14159265358979323846f

typedef float v2f __attribute__((ext_vector_type(2)));

__device__ __forceinline__ v2f pkfma(float s, v2f m, v2f a) {
    return __builtin_elementwise_fma((v2f){s, s}, m, a);
}

// ---------------------------------------------------------------------------
// Interleaved 3-way DPP wave-64 reduction stage (VALU pipe).
// After the 6-stage sequence (shr1,2,4,8 + bcast15,31) totals land in lane 63.
// ---------------------------------------------------------------------------
template <int CTRL>
__device__ __forceinline__ void red_stage3(float v[3]) {
#pragma unroll
    for (int k = 0; k < 3; ++k)
        v[k] += __int_as_float(__builtin_amdgcn_update_dpp(
            0, __float_as_int(v[k]), CTRL, 0xF, 0xF, false));
}

// Branch-free sincos(h/2) for |h| <= 1 (h is a bounded expectation value).
__device__ __forceinline__ void sincos_half(float h, float& s, float& c) {
    const float u = h * h;
    c = fmaf(u, fmaf(u, fmaf(u, -2.1701389e-5f, 2.6041667e-3f), -0.125f), 1.0f);
    s = h * fmaf(u, fmaf(u, fmaf(u, -1.5501e-6f, 2.6041667e-4f), -2.0833333e-2f), 0.5f);
}

// ---------------------------------------------------------------------------
// Kernel 1: bf16-vs-f32 detection on `angles` (U(0,pi) data).
// ---------------------------------------------------------------------------
__global__ void k_detect(const uint32_t* __restrict__ a, int* __restrict__ flag) {
    __shared__ int cnt;
    if (threadIdx.x == 0) cnt = 0;
    __syncthreads();
    uint32_t w = a[threadIdx.x];
    uint32_t e = (w >> 8) & 0xFFu;
    if (e >= 0x3Au && e <= 0x41u) atomicAdd(&cnt, 1);
    __syncthreads();
    if (threadIdx.x == 0) *flag = (cnt >= 128) ? 1 : 0;   // 1 = bf16
}

__device__ __forceinline__ float ldf(const void* p, int i, bool bf) {
    if (bf) {
        uint32_t u = (uint32_t)((const uint16_t*)p)[i];
        return __uint_as_float(u << 16);
    }
    return ((const float*)p)[i];
}

// ---------------------------------------------------------------------------
// Kernel 2: inputs -> f32 ws; precompute cos(x), sin(x) (full angle).
// ---------------------------------------------------------------------------
__global__ void k_convert(const void* ang, const void* poly, const void* fp,
                          const void* bp, const void* fc, const void* bc,
                          float* __restrict__ cs, float* __restrict__ misc,
                          const int* __restrict__ flag) {
    const bool bf = (*flag != 0);
    const int i = blockIdx.x * blockDim.x + threadIdx.x;
    if (i < NELEM) {
        float x = ldf(ang, i, bf);
        float s, c;
        __sincosf(x, &s, &c);
        cs[2 * i]     = c;
        cs[2 * i + 1] = s;
    }
    if (i < 4)                    misc[i]            = ldf(poly, i, bf);
    else if (i >= 64 && i < 100)  misc[4 + (i - 64)] = ldf(fp, i - 64, bf);
    else if (i >= 128 && i < 164) misc[40 + (i - 128)] = ldf(bp, i - 128, bf);
    else if (i == 200)            misc[76] = ldf(fc, 0, bf);
    else if (i == 201)            misc[77] = ldf(bc, 0, bf);
}

// ---------------------------------------------------------------------------
// Kernel 3: precompute M[dir] as an explicit 64x64 complex matrix.
// Mg layout: [dir][row][col][2] floats. Runs once; perf-irrelevant.
// ---------------------------------------------------------------------------
__global__ void __launch_bounds__(64) k_msetup(const float* __restrict__ misc,
                                               float* __restrict__ Mg) {
    const int p   = threadIdx.x;
    const int col = blockIdx.x & 63;
    const int dir = blockIdx.x >> 6;
    const float* poly = misc;
    const float* prm  = misc + (dir ? 40 : 4);

    float yr = (p == col) ? 1.f : 0.f;
    float yi = 0.f;

#pragma unroll
    for (int d = 0; d < 4; ++d) {
        const float th = 0.5f * PI_F * poly[d] *
                         (float)(6 - 2 * (int)__popc((unsigned)p));
        float s, c;
        __sincosf(th, &s, &c);
        const float nr = yr * c + yi * s;
        const float ni = yi * c - yr * s;
        yr = nr; yi = ni;
#pragma unroll
        for (int k = 0; k < 6; ++k) {
            const int cw = k, tw = (k + 1) % 6;
            const int src = p ^ (((p >> (5 - cw)) & 1) << (5 - tw));
            yr = __shfl(yr, src, 64);
            yi = __shfl(yi, src, 64);
        }
    }

    int idx = 0;
#pragma unroll
    for (int l = 0; l < 2; ++l) {
#pragma unroll
        for (int w = 0; w < 6; ++w) {
            float cx, sx, cy, sy, cz, sz;
            __sincosf(0.5f * prm[idx + 0], &sx, &cx);
            __sincosf(0.5f * prm[idx + 1], &sy, &cy);
            __sincosf(0.5f * prm[idx + 2], &sz, &cz);
            idx += 3;
            const float A = cy * cx, B = sy * sx, C = sy * cx, D = cy * sx;
            const float U00r = cz * A + sz * B, U00i = cz * B - sz * A;
            const float U11r = U00r,            U11i = sz * A - cz * B;
            const float Xr   = cz * C + sz * D, Xi   = sz * C - cz * D;
            const int m  = 1 << (5 - w);
            const int bb = (p >> (5 - w)) & 1;
            const float C1r = bb ? U11r : U00r;
            const float C1i = bb ? U11i : U00i;
            const float C2r = bb ? Xr : -Xr;
            const float C2i = Xi;
            const float pr = __shfl_xor(yr, m, 64);
            const float pi = __shfl_xor(yi, m, 64);
            const float nr = C1r * yr - C1i * yi + C2r * pr - C2i * pi;
            const float ni = C1r * yi + C1i * yr + C2r * pi + C2i * pr;
            yr = nr; yi = ni;
        }
#pragma unroll
        for (int k = 0; k < 5; ++k) {
            const int src = p ^ (((p >> (5 - k)) & 1) << (5 - (k + 1)));
            yr = __shfl(yr, src, 64);
            yi = __shfl(yi, src, 64);
        }
    }

    float* out = Mg + ((size_t)(dir * 64 + p) * 64 + (size_t)col) * 2;
    out[0] = yr;
    out[1] = yi;
}

// ---------------------------------------------------------------------------
// Kernel 4: recurrent sim. FOUR WAVES per chain (r8 skeleton); wave wv owns
// M columns [16wv,16wv+16) register-resident (32 VGPRs, proven).
// vs r8/r11: the measurement is SPLIT 4 ways (wave0: <Z> wires 0-2, wave1:
// <Z> 3-5, wave2: <X> 0-2, wave3: <X> 3-5) — 3 DPP chains/wave instead of
// 12, bpermutes only on waves 2-3 (6 each). Results meet in a 12-float LDS
// slab; after barrier B all waves read it with uniform b128 broadcasts and
// form z/h redundantly (12 FMAs) — h stays in VGPRs (no readlane dance).
// Two barriers/step; bet: instruction savings > barrier-B cost.
// ---------------------------------------------------------------------------
__global__ void __launch_bounds__(256, 1) k_sim(const float* __restrict__ cs,
                                                const float* __restrict__ Mg,
                                                float* __restrict__ hbuf) {
    const int tid   = threadIdx.x;
    const int lane  = tid & 63;
    const int wv    = tid >> 6;              // wave 0..3
    const int chain = blockIdx.x;            // 0..255
    const int dir   = chain >> 7;
    const int b     = chain & 127;
    float* orow = hbuf + (size_t)dir * NELEM + (size_t)b * (SEQ * NW);
    const float* csrow = cs + (size_t)b * (SEQ * NW * 2);

    __shared__ __align__(16) float  cl[SEQ * 12];   // 24 KB staged cos/sin(x)
    __shared__ __align__(16) float  zb[SEQ * NW];   // 12 KB output buffer
    __shared__ float2 pY[2][4][DIM];                // ping-pong partials, 4 KB
    __shared__ __align__(16) float  mR[12];         // measure-sum slab

    // ---- stage this chain's cos/sin rows into LDS (once) ----
    {
        const float4* src = (const float4*)csrow;   // 1536 float4
        float4* dst = (float4*)cl;
#pragma unroll
        for (int k = 0; k < 6; ++k) {
            const int idx = tid + k * 256;
            dst[idx] = src[idx];
        }
    }

    // ---- my 16 resident M columns: row = lane, cols = 16wv..16wv+15 ----
    v2f Mres[16];
    {
        const float2* mr2 =
            (const float2*)(Mg + (size_t)(dir * 64 + lane) * 128 + 32 * wv);
#pragma unroll
        for (int k = 0; k < 16; ++k) Mres[k] = (v2f){mr2[k].x, mr2[k].y};
    }

    // ---- my measurement assignment: 3 wires, Z or X ----
    const int w0  = (wv & 1) * 3;            // wire base
    const int isX = wv >> 1;                 // waves 2,3 do <X>
    int zmask3[3], bpa3[3];
#pragma unroll
    for (int k = 0; k < 3; ++k) {
        const int w = w0 + k;
        zmask3[k] = ((lane >> (5 - w)) & 1) << 31;
        bpa3[k]   = (lane ^ (1 << (5 - w))) << 2;
    }

    float h[6] = {0.f, 0.f, 0.f, 0.f, 0.f, 0.f};

    // encode h -> my 16-col matvec partial (registers only)
    auto encode_matvec = [&](v2f& acc) {
        float cw6[6], sw6[6];
#pragma unroll
        for (int w = 0; w < 6; ++w) sincos_half(h[w], sw6[w], cw6[w]);
        const float t0 = (wv & 2) ? sw6[0] : cw6[0];   // wire0 bit = wv>>1
        const float t1 = (wv & 1) ? sw6[1] : cw6[1];   // wire1 bit = wv&1
        const float A  = t0 * t1;
        float GH[4], GL[4];
        GH[0] = cw6[2] * cw6[3]; GH[1] = cw6[2] * sw6[3];
        GH[2] = sw6[2] * cw6[3]; GH[3] = sw6[2] * sw6[3];
#pragma unroll
        for (int a = 0; a < 4; ++a) GH[a] *= A;
        GL[0] = cw6[4] * cw6[5]; GL[1] = cw6[4] * sw6[5];
        GL[2] = sw6[4] * cw6[5]; GL[3] = sw6[4] * sw6[5];
        v2f y = {0.f, 0.f};
#pragma unroll
        for (int a = 0; a < 4; ++a) {
            v2f T = {0.f, 0.f};
#pragma unroll
            for (int b2 = 0; b2 < 4; ++b2)
                T = pkfma(GL[b2], Mres[4 * a + b2], T);
            y = pkfma(GH[a], T, y);
        }
        acc = y;
    };

    // walking pointers
    const float* cp = cl + (dir ? (SEQ - 1) * 12 : 0);
    const int   cstep = dir ? -12 : 12;
    float*       zp = zb + (dir ? (SEQ - 1) * NW : 0);
    const int   zstep = dir ? -NW : NW;

    __syncthreads();                         // staging + Mres visible

    // ---- peel: partial for the t=0 state (h = 0) ----
    {
        v2f acc;
        encode_matvec(acc);
        pY[0][wv][lane] = (float2){acc.x, acc.y};
    }
    __syncthreads();                         // barrier A

    for (int t = 0; t < SEQ; ++t) {
        const int buf = t & 1;

        // phase 1: gather the 4 partials -> full y (one latency window)
        const float2 y0 = pY[buf][0][lane], y1 = pY[buf][1][lane];
        const float2 y2 = pY[buf][2][lane], y3 = pY[buf][3][lane];
        const float yr = (y0.x + y1.x) + (y2.x + y3.x);
        const float yi = (y0.y + y1.y) + (y2.y + y3.y);

        // phase 2: my 3 reductions (wave-uniform branch)
        float v3[3];
        if (isX) {
            float pr[3], pi[3];
#pragma unroll
            for (int k = 0; k < 3; ++k)
                pr[k] = __int_as_float(
                    __builtin_amdgcn_ds_bpermute(bpa3[k], __float_as_int(yr)));
#pragma unroll
            for (int k = 0; k < 3; ++k)
                pi[k] = __int_as_float(
                    __builtin_amdgcn_ds_bpermute(bpa3[k], __float_as_int(yi)));
#pragma unroll
            for (int k = 0; k < 3; ++k) v3[k] = yr * pr[k] + yi * pi[k];
        } else {
            const float q = yr * yr + yi * yi;
#pragma unroll
            for (int k = 0; k < 3; ++k)
                v3[k] = __int_as_float(__float_as_int(q) ^ zmask3[k]);
        }
        red_stage3<0x111>(v3);   // row_shr:1
        red_stage3<0x112>(v3);   // row_shr:2
        red_stage3<0x114>(v3);   // row_shr:4
        red_stage3<0x118>(v3);   // row_shr:8
        red_stage3<0x142>(v3);   // row_bcast:15
        red_stage3<0x143>(v3);   // row_bcast:31

        // phase 3: lane63 posts 3 sums -> slab slot [wv*3 .. wv*3+2]
        if (lane == 63) {
            mR[wv * 3 + 0] = v3[0];
            mR[wv * 3 + 1] = v3[1];
            mR[wv * 3 + 2] = v3[2];
        }
        __syncthreads();                     // barrier B

        // phase 5: all waves read slab + cos/sin (uniform b128 broadcasts)
        const float4 xq0 = ((const float4*)cp)[0];
        const float4 xq1 = ((const float4*)cp)[1];
        const float4 xq2 = ((const float4*)cp)[2];
        cp += cstep;
        const float4 m0 = ((const float4*)mR)[0];   // Z0 Z1 Z2 Z3
        const float4 m1 = ((const float4*)mR)[1];   // Z4 Z5 X0 X1
        const float4 m2 = ((const float4*)mR)[2];   // X2 X3 X4 X5

        float z[6];
        z[0] = xq0.x * m0.x - xq0.y * m1.z;
        z[1] = xq0.z * m0.y - xq0.w * m1.w;
        z[2] = xq1.x * m0.z - xq1.y * m2.x;
        z[3] = xq1.z * m0.w - xq1.w * m2.y;
        z[4] = xq2.x * m1.x - xq2.y * m2.z;
        z[5] = xq2.z * m1.y - xq2.w * m2.w;
#pragma unroll
        for (int w = 0; w < 6; ++w) h[w] = z[w];   // h stays in VGPRs

        if (tid == 63) {                     // one lane buffers outputs
#pragma unroll
            for (int w = 0; w < 6; ++w) zp[w] = z[w];
        }
        zp += zstep;

        // phase 6-7: next state's partial into the other buffer
        {
            v2f acc;
            encode_matvec(acc);
            pY[buf ^ 1][wv][lane] = (float2){acc.x, acc.y};
        }
        __syncthreads();                     // barrier A
    }

    // ---- bulk store outputs: 768 float4 over 256 threads ----
    {
        const float4* zs4 = (const float4*)zb;
        float4* go = (float4*)orow;
#pragma unroll
        for (int k = 0; k < 3; ++k) {
            const int idx = tid + k * 256;
            go[idx] = zs4[idx];
        }
    }
}

// ---------------------------------------------------------------------------
// Kernel 5: out = sigmoid(fc)*h_fwd + sigmoid(bc)*h_bwd, dtype per flag.
// ---------------------------------------------------------------------------
__global__ void k_combine(const float* __restrict__ hbuf,
                          const float* __restrict__ misc,
                          void* __restrict__ out, const int* __restrict__ flag) {
    const int i = blockIdx.x * blockDim.x + threadIdx.x;
    if (i >= NELEM) return;
    const float sf = 1.f / (1.f + __expf(-misc[76]));
    const float sb = 1.f / (1.f + __expf(-misc[77]));
    const float v = sf * hbuf[i] + sb * hbuf[NELEM + i];
    if (*flag) ((__hip_bfloat16*)out)[i] = __float2bfloat16(v);
    else       ((float*)out)[i] = v;
}

// ---------------------------------------------------------------------------
extern "C" void kernel_launch(void* const* d_in, const int* in_sizes, int n_in,
                              void* d_out, int out_size, void* d_ws, size_t ws_size,
                              hipStream_t stream) {
    const void* ang  = d_in[0];
    const void* poly = d_in[1];
    const void* fp   = d_in[2];
    const void* bp   = d_in[3];
    const void* fc   = d_in[4];
    const void* bc   = d_in[5];

    // ws (floats): pad[32] | cs[2*NELEM] | misc[128] | hbuf[2*NELEM] |
    //              M[16384] | flag
    float* cs   = (float*)d_ws + 32;
    float* misc = cs + 2 * NELEM;
    float* hbuf = misc + 128;
    float* Mg   = hbuf + 2 * NELEM;
    int*   flag = (int*)(Mg + 2 * 64 * 64 * 2);

    k_detect<<<1, 256, 0, stream>>>((const uint32_t*)ang, flag);
    k_convert<<<(NELEM + 255) / 256, 256, 0, stream>>>(ang, poly, fp, bp, fc, bc,
                                                       cs, misc, flag);
    k_msetup<<<128, 64, 0, stream>>>(misc, Mg);
    k_sim<<<256, 256, 0, stream>>>(cs, Mg, hbuf);
    k_combine<<<(NELEM + 255) / 256, 256, 0, stream>>>(hbuf, misc, d_out, flag);
}

// Round 13
// 345.761 us; speedup vs baseline: 1.2843x; 1.0542x over previous
//
#include <hip/hip_runtime.h>
#include <hip/hip_bf16.h>
#include <stdint.h>

#define BATCH 128
#define SEQ   512
#define NW    6
#define DIM   64
#define NELEM (BATCH * SEQ * NW)   // 393216
#define PI_F  3.14159265358979323846f
#define NCONV 1536                 // convert blocks; msetup blocks follow

typedef float v2f __attribute__((ext_vector_type(2)));

__device__ __forceinline__ v2f pkfma(float s, v2f m, v2f a) {
    return __builtin_elementwise_fma((v2f){s, s}, m, a);
}

// ---------------------------------------------------------------------------
// Interleaved 3-way DPP wave-64 reduction stage. After shr1,2,4,8 +
// bcast15,31 the totals land in lane 63.
// ---------------------------------------------------------------------------
template <int CTRL>
__device__ __forceinline__ void red_stage3(float v[3]) {
#pragma unroll
    for (int k = 0; k < 3; ++k)
        v[k] += __int_as_float(__builtin_amdgcn_update_dpp(
            0, __float_as_int(v[k]), CTRL, 0xF, 0xF, false));
}

// Branch-free sincos(h/2), |h| <= 1. Trimmed to the bf16-output tolerance:
// cos err <= 2.2e-5, sin err <= 1.6e-6 (threshold 2.4e-2, output bf16).
__device__ __forceinline__ void sincos_half(float h, float& s, float& c) {
    const float u = h * h;
    c = fmaf(u, fmaf(u, 2.6041667e-3f, -0.125f), 1.0f);
    s = h * fmaf(u, fmaf(u, 2.6041667e-4f, -2.0833333e-2f), 0.5f);
}

__device__ __forceinline__ float ldf(const void* p, int i, bool bf) {
    if (bf) {
        uint32_t u = (uint32_t)((const uint16_t*)p)[i];
        return __uint_as_float(u << 16);
    }
    return ((const float*)p)[i];
}

// ---------------------------------------------------------------------------
// Kernel 1 (fused detect + convert + msetup):
//  - every block self-detects bf16-vs-f32 from the first 256 words of angles
//  - blocks [0,NCONV): cs[i] = {cos,sin}(x_i); misc fills; block0 posts flag
//  - blocks [NCONV, NCONV+32): 4 waves/block evolve one (dir,col) basis
//    column each -> Mg  (params read directly from d_in, no dependency)
// ---------------------------------------------------------------------------
__global__ void k_prep(const void* ang, const void* poly, const void* fp,
                       const void* bp, const void* fc, const void* bc,
                       float* __restrict__ cs, float* __restrict__ misc,
                       float* __restrict__ Mg, int* __restrict__ flag) {
    __shared__ int cnt;
    if (threadIdx.x == 0) cnt = 0;
    __syncthreads();
    {
        uint32_t w = ((const uint32_t*)ang)[threadIdx.x & 255];
        uint32_t e = (w >> 8) & 0xFFu;
        if (e >= 0x3Au && e <= 0x41u) atomicAdd(&cnt, 1);
    }
    __syncthreads();
    const bool bf = (cnt >= 128);

    if (blockIdx.x < NCONV) {
        const int i = blockIdx.x * 256 + threadIdx.x;
        if (i < NELEM) {
            float x = ldf(ang, i, bf);
            float s, c;
            __sincosf(x, &s, &c);
            cs[2 * i]     = c;
            cs[2 * i + 1] = s;
        }
        if (i == 200)      misc[76] = ldf(fc, 0, bf);
        else if (i == 201) misc[77] = ldf(bc, 0, bf);
        else if (i == 202) *flag = bf ? 1 : 0;
        return;
    }

    // ---- msetup path: 4 columns per block (one per wave) ----
    const int lane = threadIdx.x & 63;
    const int tix  = (blockIdx.x - NCONV) * 4 + (threadIdx.x >> 6);
    const int dir  = tix >> 6;
    const int col  = tix & 63;
    const void* prm = dir ? bp : fp;
    const int p = lane;

    float yr = (p == col) ? 1.f : 0.f;
    float yi = 0.f;

#pragma unroll
    for (int d = 0; d < 4; ++d) {
        const float th = 0.5f * PI_F * ldf(poly, d, bf) *
                         (float)(6 - 2 * (int)__popc((unsigned)p));
        float s, c;
        __sincosf(th, &s, &c);
        const float nr = yr * c + yi * s;
        const float ni = yi * c - yr * s;
        yr = nr; yi = ni;
#pragma unroll
        for (int k = 0; k < 6; ++k) {
            const int cw = k, tw = (k + 1) % 6;
            const int src = p ^ (((p >> (5 - cw)) & 1) << (5 - tw));
            yr = __shfl(yr, src, 64);
            yi = __shfl(yi, src, 64);
        }
    }

    int idx = 0;
#pragma unroll
    for (int l = 0; l < 2; ++l) {
#pragma unroll
        for (int w = 0; w < 6; ++w) {
            float cx, sx, cy, sy, cz, sz;
            __sincosf(0.5f * ldf(prm, idx + 0, bf), &sx, &cx);
            __sincosf(0.5f * ldf(prm, idx + 1, bf), &sy, &cy);
            __sincosf(0.5f * ldf(prm, idx + 2, bf), &sz, &cz);
            idx += 3;
            const float A = cy * cx, B = sy * sx, C = sy * cx, D = cy * sx;
            const float U00r = cz * A + sz * B, U00i = cz * B - sz * A;
            const float U11r = U00r,            U11i = sz * A - cz * B;
            const float Xr   = cz * C + sz * D, Xi   = sz * C - cz * D;
            const int m  = 1 << (5 - w);
            const int bb = (p >> (5 - w)) & 1;
            const float C1r = bb ? U11r : U00r;
            const float C1i = bb ? U11i : U00i;
            const float C2r = bb ? Xr : -Xr;
            const float C2i = Xi;
            const float pr = __shfl_xor(yr, m, 64);
            const float pi = __shfl_xor(yi, m, 64);
            const float nr = C1r * yr - C1i * yi + C2r * pr - C2i * pi;
            const float ni = C1r * yi + C1i * yr + C2r * pi + C2i * pr;
            yr = nr; yi = ni;
        }
#pragma unroll
        for (int k = 0; k < 5; ++k) {
            const int src = p ^ (((p >> (5 - k)) & 1) << (5 - (k + 1)));
            yr = __shfl(yr, src, 64);
            yi = __shfl(yi, src, 64);
        }
    }

    float* out = Mg + ((size_t)(dir * 64 + p) * 64 + (size_t)col) * 2;
    out[0] = yr;
    out[1] = yi;
}

// ---------------------------------------------------------------------------
// Kernel 2: recurrent sim — r12 structure (4 waves, split measurement, two
// barriers) with micro-opts:
//  - xq cos/sin reads hoisted into the pY-read LDS window (they were on the
//    post-barrier-B critical path; they depend on nothing in-loop)
//  - own matvec partial kept in registers (3 pY reads, not 4)
//  - trimmed sincos polynomials
// ---------------------------------------------------------------------------
__global__ void __launch_bounds__(256, 1) k_sim(const float* __restrict__ cs,
                                                const float* __restrict__ Mg,
                                                float* __restrict__ hbuf) {
    const int tid   = threadIdx.x;
    const int lane  = tid & 63;
    const int wv    = tid >> 6;              // wave 0..3
    const int chain = blockIdx.x;            // 0..255
    const int dir   = chain >> 7;
    const int b     = chain & 127;
    float* orow = hbuf + (size_t)dir * NELEM + (size_t)b * (SEQ * NW);
    const float* csrow = cs + (size_t)b * (SEQ * NW * 2);

    __shared__ __align__(16) float  cl[SEQ * 12];   // 24 KB staged cos/sin(x)
    __shared__ __align__(16) float  zb[SEQ * NW];   // 12 KB output buffer
    __shared__ float2 pY[2][4][DIM];                // ping-pong partials, 4 KB
    __shared__ __align__(16) float  mR[12];         // measure-sum slab

    // ---- stage this chain's cos/sin rows into LDS (once) ----
    {
        const float4* src = (const float4*)csrow;   // 1536 float4
        float4* dst = (float4*)cl;
#pragma unroll
        for (int k = 0; k < 6; ++k) {
            const int idx = tid + k * 256;
            dst[idx] = src[idx];
        }
    }

    // ---- my 16 resident M columns: row = lane, cols = 16wv..16wv+15 ----
    v2f Mres[16];
    {
        const float2* mr2 =
            (const float2*)(Mg + (size_t)(dir * 64 + lane) * 128 + 32 * wv);
#pragma unroll
        for (int k = 0; k < 16; ++k) Mres[k] = (v2f){mr2[k].x, mr2[k].y};
    }

    // ---- my measurement assignment: 3 wires, Z or X ----
    const int w0  = (wv & 1) * 3;            // wire base
    const int isX = wv >> 1;                 // waves 2,3 do <X>
    int zmask3[3], bpa3[3];
#pragma unroll
    for (int k = 0; k < 3; ++k) {
        const int w = w0 + k;
        zmask3[k] = ((lane >> (5 - w)) & 1) << 31;
        bpa3[k]   = (lane ^ (1 << (5 - w))) << 2;
    }
    const int ow0 = wv ^ 1, ow1 = wv ^ 2, ow2 = wv ^ 3;   // other waves

    float h[6] = {0.f, 0.f, 0.f, 0.f, 0.f, 0.f};

    // encode h -> my 16-col matvec partial (registers only)
    auto encode_matvec = [&](v2f& acc) {
        float cw6[6], sw6[6];
#pragma unroll
        for (int w = 0; w < 6; ++w) sincos_half(h[w], sw6[w], cw6[w]);
        const float t0 = (wv & 2) ? sw6[0] : cw6[0];   // wire0 bit = wv>>1
        const float t1 = (wv & 1) ? sw6[1] : cw6[1];   // wire1 bit = wv&1
        const float A  = t0 * t1;
        float GH[4], GL[4];
        GH[0] = cw6[2] * cw6[3]; GH[1] = cw6[2] * sw6[3];
        GH[2] = sw6[2] * cw6[3]; GH[3] = sw6[2] * sw6[3];
#pragma unroll
        for (int a = 0; a < 4; ++a) GH[a] *= A;
        GL[0] = cw6[4] * cw6[5]; GL[1] = cw6[4] * sw6[5];
        GL[2] = sw6[4] * cw6[5]; GL[3] = sw6[4] * sw6[5];
        v2f y = {0.f, 0.f};
#pragma unroll
        for (int a = 0; a < 4; ++a) {
            v2f T = {0.f, 0.f};
#pragma unroll
            for (int b2 = 0; b2 < 4; ++b2)
                T = pkfma(GL[b2], Mres[4 * a + b2], T);
            y = pkfma(GH[a], T, y);
        }
        acc = y;
    };

    // walking pointers
    const float* cp = cl + (dir ? (SEQ - 1) * 12 : 0);
    const int   cstep = dir ? -12 : 12;
    float*       zp = zb + (dir ? (SEQ - 1) * NW : 0);
    const int   zstep = dir ? -NW : NW;

    __syncthreads();                         // staging + Mres visible

    // ---- peel: partial for the t=0 state (h = 0) ----
    v2f myacc;
    encode_matvec(myacc);
    pY[0][wv][lane] = (float2){myacc.x, myacc.y};
    __syncthreads();                         // barrier A

    for (int t = 0; t < SEQ; ++t) {
        const int buf = t & 1;

        // one batched LDS window: 3 partner partials + this step's cos/sin
        // (xq hoisted off the post-barrier-B critical path)
        const float2 yA = pY[buf][ow0][lane];
        const float2 yB = pY[buf][ow1][lane];
        const float2 yC = pY[buf][ow2][lane];
        const float4 xq0 = ((const float4*)cp)[0];
        const float4 xq1 = ((const float4*)cp)[1];
        const float4 xq2 = ((const float4*)cp)[2];
        cp += cstep;

        const float yr = (myacc.x + yA.x) + (yB.x + yC.x);
        const float yi = (myacc.y + yA.y) + (yB.y + yC.y);

        // my 3 reductions (wave-uniform branch)
        float v3[3];
        if (isX) {
            float pr[3], pi[3];
#pragma unroll
            for (int k = 0; k < 3; ++k)
                pr[k] = __int_as_float(
                    __builtin_amdgcn_ds_bpermute(bpa3[k], __float_as_int(yr)));
#pragma unroll
            for (int k = 0; k < 3; ++k)
                pi[k] = __int_as_float(
                    __builtin_amdgcn_ds_bpermute(bpa3[k], __float_as_int(yi)));
#pragma unroll
            for (int k = 0; k < 3; ++k) v3[k] = yr * pr[k] + yi * pi[k];
        } else {
            const float q = yr * yr + yi * yi;
#pragma unroll
            for (int k = 0; k < 3; ++k)
                v3[k] = __int_as_float(__float_as_int(q) ^ zmask3[k]);
        }
        red_stage3<0x111>(v3);   // row_shr:1
        red_stage3<0x112>(v3);   // row_shr:2
        red_stage3<0x114>(v3);   // row_shr:4
        red_stage3<0x118>(v3);   // row_shr:8
        red_stage3<0x142>(v3);   // row_bcast:15
        red_stage3<0x143>(v3);   // row_bcast:31

        if (lane == 63) {
            mR[wv * 3 + 0] = v3[0];
            mR[wv * 3 + 1] = v3[1];
            mR[wv * 3 + 2] = v3[2];
        }
        __syncthreads();                     // barrier B

        // slab read is now the only post-B LDS dependency
        const float4 m0 = ((const float4*)mR)[0];   // Z0 Z1 Z2 Z3
        const float4 m1 = ((const float4*)mR)[1];   // Z4 Z5 X0 X1
        const float4 m2 = ((const float4*)mR)[2];   // X2 X3 X4 X5

        float z[6];
        z[0] = xq0.x * m0.x - xq0.y * m1.z;
        z[1] = xq0.z * m0.y - xq0.w * m1.w;
        z[2] = xq1.x * m0.z - xq1.y * m2.x;
        z[3] = xq1.z * m0.w - xq1.w * m2.y;
        z[4] = xq2.x * m1.x - xq2.y * m2.z;
        z[5] = xq2.z * m1.y - xq2.w * m2.w;

        if (tid == 63) {                     // one lane buffers outputs
#pragma unroll
            for (int w = 0; w < 6; ++w) zp[w] = z[w];
        }
        zp += zstep;
#pragma unroll
        for (int w = 0; w < 6; ++w) h[w] = z[w];   // h stays in VGPRs

        // next state's partial into the other buffer
        encode_matvec(myacc);
        pY[buf ^ 1][wv][lane] = (float2){myacc.x, myacc.y};
        __syncthreads();                     // barrier A
    }

    // ---- bulk store outputs: 768 float4 over 256 threads ----
    {
        const float4* zs4 = (const float4*)zb;
        float4* go = (float4*)orow;
#pragma unroll
        for (int k = 0; k < 3; ++k) {
            const int idx = tid + k * 256;
            go[idx] = zs4[idx];
        }
    }
}

// ---------------------------------------------------------------------------
// Kernel 3: out = sigmoid(fc)*h_fwd + sigmoid(bc)*h_bwd, dtype per flag.
// ---------------------------------------------------------------------------
__global__ void k_combine(const float* __restrict__ hbuf,
                          const float* __restrict__ misc,
                          void* __restrict__ out, const int* __restrict__ flag) {
    const int i = blockIdx.x * blockDim.x + threadIdx.x;
    if (i >= NELEM) return;
    const float sf = 1.f / (1.f + __expf(-misc[76]));
    const float sb = 1.f / (1.f + __expf(-misc[77]));
    const float v = sf * hbuf[i] + sb * hbuf[NELEM + i];
    if (*flag) ((__hip_bfloat16*)out)[i] = __float2bfloat16(v);
    else       ((float*)out)[i] = v;
}

// ---------------------------------------------------------------------------
extern "C" void kernel_launch(void* const* d_in, const int* in_sizes, int n_in,
                              void* d_out, int out_size, void* d_ws, size_t ws_size,
                              hipStream_t stream) {
    const void* ang  = d_in[0];
    const void* poly = d_in[1];
    const void* fp   = d_in[2];
    const void* bp   = d_in[3];
    const void* fc   = d_in[4];
    const void* bc   = d_in[5];

    // ws (floats): pad[32] | cs[2*NELEM] | misc[128] | hbuf[2*NELEM] |
    //              M[16384] | flag
    float* cs   = (float*)d_ws + 32;
    float* misc = cs + 2 * NELEM;
    float* hbuf = misc + 128;
    float* Mg   = hbuf + 2 * NELEM;
    int*   flag = (int*)(Mg + 2 * 64 * 64 * 2);

    k_prep<<<NCONV + 32, 256, 0, stream>>>(ang, poly, fp, bp, fc, bc,
                                           cs, misc, Mg, flag);
    k_sim<<<256, 256, 0, stream>>>(cs, Mg, hbuf);
    k_combine<<<(NELEM + 255) / 256, 256, 0, stream>>>(hbuf, misc, d_out, flag);
}